// Round 8
// baseline (118.767 us; speedup 1.0000x reference)
//
#include <hip/hip_runtime.h>
#include <math.h>

#define NB 8
#define NQ 256
#define NK 256
#define DIN 10
#define FDIM 64
#define HIDDEN 256
#define NH 8

#define FSTRIDE 64    // shorts per feat row; XOR-swizzled 8-short col-blocks, no pad
#define HSTRIDE 264   // shorts per h row (256 + 8 pad) -> 528 B
#define W2S 264       // shorts per w2 row (8 rows, padded -> 528 B, breaks 8-way conflict)

typedef float f32x4 __attribute__((ext_vector_type(4)));
typedef short bf16x8 __attribute__((ext_vector_type(8)));

// fast float->bf16: round-to-nearest, ties away (2 instrs)
__device__ __forceinline__ short f2bf(float f) {
    return (short)((__float_as_uint(f) + 0x8000u) >> 16);
}
// pack two floats -> two bf16 in one dword (2 adds + 1 perm)
__device__ __forceinline__ unsigned pack2(float a, float b) {
    unsigned ua = __float_as_uint(a) + 0x8000u;   // -> low half
    unsigned ub = __float_as_uint(b) + 0x8000u;   // -> high half
    return __builtin_amdgcn_perm(ub, ua, 0x07060302);
}

__device__ __forceinline__ void four4(float x, float* dst) {
    float s1 = __sinf(x), c1 = __cosf(x);
    float s2 = 2.f * s1 * c1, c2 = 1.f - 2.f * s1 * s1;
    float s4 = 2.f * s2 * c2, c4 = 1.f - 2.f * s2 * s2;
    float s8 = 2.f * s4 * c4, c8 = 1.f - 2.f * s4 * s4;
    dst[0] = s1; dst[1] = s2; dst[2] = s4; dst[3] = s8;
    dst[4] = c1; dst[5] = c2; dst[6] = c4; dst[7] = c8;
}
__device__ __forceinline__ void four2(float x, float* dst) {
    float s1 = __sinf(x), c1 = __cosf(x);
    dst[0] = s1; dst[1] = 2.f * s1 * c1;
    dst[2] = c1; dst[3] = 1.f - 2.f * s1 * s1;
}

// Block = one (b,i): 256 pairs, 4 waves, 8 half-chunks of 32 pairs.
// GEMM1 is TRANSPOSED: D[h][p] = sum_k W1[k][h]*feat[p][k]. A = W1^T (the
// same registers/loads as the old B-frag — A/B frags share the lane map),
// B = feat^T (the same feat_s read as the old A-frag). D: row=quad*4+r is
// now HIDDEN, col=lane15 is PAIR -> each lane's 4 acc regs are hidden-adjacent
// for one pair -> silu results pack into ONE ds_write_b64 (8 writes/hc vs 32).
// GEMM2 unchanged (h_s pair-major, hidden-contiguous).
// LDS 53888 B -> 3 blocks/CU.
__global__ __launch_bounds__(256, 3) void relfeat_mfma_kernel(
    const float* __restrict__ q, const float* __restrict__ k,
    const float* __restrict__ W1, const float* __restrict__ b1,
    const float* __restrict__ W2, const float* __restrict__ b2,
    float* __restrict__ out)
{
    __shared__ __align__(16) short feat_s[NK * FSTRIDE];   // 32768 B
    __shared__ __align__(16) short h_s[32 * HSTRIDE];      // 16896 B
    __shared__ __align__(16) short w2_s[8 * W2S];          //  4224 B

    const int t = threadIdx.x;
    const int wave = t >> 6;
    const int lane15 = t & 15;
    const int quad = (t >> 4) & 3;
    const int b = blockIdx.x >> 8;
    const int i = blockIdx.x & (NQ - 1);

    // ---- features for pair j = t (r5-proven math), swizzled immediate store ----
    {
        const float* kp = k + ((size_t)b * NK + t) * DIN;
        const float k0 = kp[0], k3 = kp[3], k4 = kp[4], k5 = kp[5], k6 = kp[6],
                    k7 = kp[7], k8 = kp[8];
        const float* qp = q + ((size_t)b * NQ + i) * DIN;
        const float q0 = qp[0], q3 = qp[3], q4 = qp[4], q5 = qp[5], q6 = qp[6],
                    q7 = qp[7], q8 = qp[8];

        const float dpx = k3 - q3, dpy = k4 - q4;
        const float dvx = k5 - q5, dvy = k6 - q6;
        const float dist = sqrtf(dpx * dpx + dpy * dpy + 1e-6f);
        const float inv_dist = 1.0f / (dist + 0.1f);
        const float inv_d2 = 1.0f / (dist + 1e-6f);
        const float bear_x = dpx * inv_d2, bear_y = dpy * inv_d2;
        const float ata = bear_x * q7 + bear_y * q8;
        const float aspect = bear_x * k7 + bear_y * k8;
        const float dot_dp_dv = dpx * dvx + dpy * dvy;
        const float speed_sq = dvx * dvx + dvy * dvy;
        const float ttca = tanhf(fmaxf(0.f, -dot_dp_dv / (speed_sq + 1e-6f)));
        const float same_team = (q0 == k0) ? 1.f : 0.f;
        const float q_speed = sqrtf(q5 * q5 + q6 * q6);
        const float k_speed = sqrtf(k5 * k5 + k6 * k6);
        const float delta_speed = k_speed - q_speed;

        float feat[FDIM];
        four4(dist,        feat + 0);
        four4(inv_dist,    feat + 8);
        four4(ata,         feat + 16);
        four4(aspect,      feat + 24);
        four2(dpx,         feat + 32);
        four2(dpy,         feat + 36);
        four2(dvx,         feat + 40);
        four2(dvy,         feat + 44);
        four2(ttca,        feat + 48);
        four2(dist,        feat + 52);
        four2(same_team,   feat + 56);
        four2(delta_speed, feat + 60);

        const int sw = t & 7;  // row-dependent XOR swizzle of 8-short blocks
#pragma unroll
        for (int c8 = 0; c8 < 8; ++c8) {
            uint4 v;
            v.x = pack2(feat[c8 * 8 + 0], feat[c8 * 8 + 1]);
            v.y = pack2(feat[c8 * 8 + 2], feat[c8 * 8 + 3]);
            v.z = pack2(feat[c8 * 8 + 4], feat[c8 * 8 + 5]);
            v.w = pack2(feat[c8 * 8 + 6], feat[c8 * 8 + 7]);
            *(uint4*)&feat_s[t * FSTRIDE + ((c8 ^ sw) * 8)] = v;
        }
    }

    // ---- stage W2^T (o-major, 8 rows, padded stride): w2_s[o][k] = W2[k][o] ----
#pragma unroll
    for (int o = 0; o < NH; ++o) w2_s[o * W2S + t] = f2bf(W2[t * NH + o]);

    // ---- W1 fragments (now the A operand; same loads as before, L2-hot) ----
    // w1f[nt][ks] lane value: A[m=lane15][k=quad*8+e] = W1[ks*32+quad*8+e][n0+nt*16+lane15]
    const int n0 = wave * 64;
    bf16x8 w1f[4][2];
#pragma unroll
    for (int nt = 0; nt < 4; ++nt)
#pragma unroll
        for (int ks = 0; ks < 2; ++ks) {
            const float* wp = W1 + (size_t)(ks * 32 + quad * 8) * HIDDEN
                              + (n0 + nt * 16 + lane15);
            bf16x8 v;
#pragma unroll
            for (int e = 0; e < 8; ++e) v[e] = f2bf(wp[(size_t)e * HIDDEN]);
            w1f[nt][ks] = v;
        }
    // bias per (nt, r): hidden = n0 + nt*16 + quad*4 + r  -> float4 per nt
    float4 b1q[4];
#pragma unroll
    for (int nt = 0; nt < 4; ++nt)
        b1q[nt] = *(const float4*)&b1[n0 + nt * 16 + quad * 4];
    const float b2v = (lane15 < NH) ? b2[lane15] : 0.f;

    __syncthreads();  // feat_s + w2_s ready

    // ---- main loop: 8 half-chunks of 32 pairs ----
    const int swr = lane15 & 7;  // row&7 for feat B-frag reads
#pragma unroll 1
    for (int hc = 0; hc < 8; ++hc) {
        const int p0h = hc * 32;

        // GEMM1' : acc[nt][mt] -> D[hidden=n0+nt*16+quad*4+r][pair=p0h+mt*16+lane15]
        f32x4 acc[4][2];
#pragma unroll
        for (int nt = 0; nt < 4; ++nt)
#pragma unroll
            for (int mt = 0; mt < 2; ++mt)
                acc[nt][mt] = (f32x4){b1q[nt].x, b1q[nt].y, b1q[nt].z, b1q[nt].w};
#pragma unroll
        for (int ks = 0; ks < 2; ++ks)
#pragma unroll
            for (int mt = 0; mt < 2; ++mt) {
                const int row = p0h + mt * 16 + lane15;
                const bf16x8 fb = *(const bf16x8*)
                    &feat_s[row * FSTRIDE + (((ks * 4 + quad) ^ swr) * 8)];
#pragma unroll
                for (int nt = 0; nt < 4; ++nt)
                    acc[nt][mt] = __builtin_amdgcn_mfma_f32_16x16x32_bf16(
                        w1f[nt][ks], fb, acc[nt][mt], 0, 0, 0);
            }

        // silu -> pack 4 hidden-adjacent bf16 -> ONE ds_write_b64 per (nt,mt)
#pragma unroll
        for (int nt = 0; nt < 4; ++nt)
#pragma unroll
            for (int mt = 0; mt < 2; ++mt) {
                const int pair = mt * 16 + lane15;
                const int hbase = n0 + nt * 16 + quad * 4;
                float s[4];
#pragma unroll
                for (int r = 0; r < 4; ++r) {
                    const float pv = acc[nt][mt][r];
                    const float e = __builtin_amdgcn_exp2f(pv * -1.44269504f);
                    s[r] = pv * __builtin_amdgcn_rcpf(1.f + e);
                }
                uint2 pk;
                pk.x = pack2(s[0], s[1]);
                pk.y = pack2(s[2], s[3]);
                *(uint2*)&h_s[pair * HSTRIDE + hbase] = pk;
            }
        __syncthreads();  // h_s(hc) ready

        // GEMM2: waves 0,1 each take one 16-pair M-tile; K=256
        if (wave < 2) {
            const int pw = wave * 16;
            f32x4 acc2 = (f32x4){b2v, b2v, b2v, b2v};
#pragma unroll
            for (int ks = 0; ks < 8; ++ks) {
                const bf16x8 ha = *(const bf16x8*)&h_s[(pw + lane15) * HSTRIDE
                                                        + ks * 32 + quad * 8];
                const bf16x8 wb = *(const bf16x8*)&w2_s[(lane15 & 7) * W2S
                                                         + ks * 32 + quad * 8];
                acc2 = __builtin_amdgcn_mfma_f32_16x16x32_bf16(ha, wb, acc2, 0, 0, 0);
            }
            if (lane15 < NH) {
                float* op = out + (((size_t)b * NH + lane15) * NQ + i) * NK
                            + (p0h + pw + quad * 4);
                *(float4*)op = make_float4(acc2[0], acc2[1], acc2[2], acc2[3]);
            }
        }
        __syncthreads();  // h_s consumed before next half-chunk overwrites
    }
}

extern "C" void kernel_launch(void* const* d_in, const int* in_sizes, int n_in,
                              void* d_out, int out_size, void* d_ws, size_t ws_size,
                              hipStream_t stream) {
    const float* q  = (const float*)d_in[0];
    const float* k  = (const float*)d_in[1];
    const float* W1 = (const float*)d_in[2];
    const float* b1 = (const float*)d_in[3];
    const float* W2 = (const float*)d_in[4];
    const float* b2 = (const float*)d_in[5];
    float* out = (float*)d_out;

    dim3 grid(NB * NQ);   // 2048 blocks: one per (b, i)
    dim3 block(NK);       // 256 threads = 4 waves
    relfeat_mfma_kernel<<<grid, block, 0, stream>>>(q, k, W1, b1, W2, b2, out);
}

// Round 9
// 116.262 us; speedup vs baseline: 1.0215x; 1.0215x over previous
//
#include <hip/hip_runtime.h>
#include <math.h>

#define NB 8
#define NQ 256
#define NK 256
#define DIN 10
#define FDIM 64
#define HIDDEN 256
#define NH 8

#define FSTRIDE 64    // shorts per feat row; XOR-swizzled 8-short col-blocks, no pad
#define HSTRIDE 264   // shorts per h row (256 + 8 pad) -> 528 B
#define W2S 264       // shorts per w2 row (8 rows, padded -> 528 B)

typedef float f32x4 __attribute__((ext_vector_type(4)));
typedef short bf16x8 __attribute__((ext_vector_type(8)));

// fast float->bf16: round-to-nearest, ties away (2 instrs)
__device__ __forceinline__ short f2bf(float f) {
    return (short)((__float_as_uint(f) + 0x8000u) >> 16);
}
// pack two floats -> two bf16 in one dword (2 adds + 1 perm)
__device__ __forceinline__ unsigned pack2(float a, float b) {
    unsigned ua = __float_as_uint(a) + 0x8000u;   // -> low half
    unsigned ub = __float_as_uint(b) + 0x8000u;   // -> high half
    return __builtin_amdgcn_perm(ub, ua, 0x07060302);
}

__device__ __forceinline__ void four4(float x, float* dst) {
    float s1 = __sinf(x), c1 = __cosf(x);
    float s2 = 2.f * s1 * c1, c2 = 1.f - 2.f * s1 * s1;
    float s4 = 2.f * s2 * c2, c4 = 1.f - 2.f * s2 * s2;
    float s8 = 2.f * s4 * c4, c8 = 1.f - 2.f * s4 * s4;
    dst[0] = s1; dst[1] = s2; dst[2] = s4; dst[3] = s8;
    dst[4] = c1; dst[5] = c2; dst[6] = c4; dst[7] = c8;
}
__device__ __forceinline__ void four2(float x, float* dst) {
    float s1 = __sinf(x), c1 = __cosf(x);
    dst[0] = s1; dst[1] = 2.f * s1 * c1;
    dst[2] = c1; dst[3] = 1.f - 2.f * s1 * s1;
}

// Block = one (b,i): 256 pairs, 4 waves, 4 chunks of 64 pairs.
// GEMM1 TRANSPOSED (r8-proven): D[h][p], A = W1^T frags in regs, B = feat^T
// from swizzled feat_s; lane's 4 acc regs are hidden-adjacent for one pair
// -> silu packs into one ds_write_b64.
// GEMM2: 64 pairs/chunk -> one 16-pair M-tile per wave (ALL waves busy).
// Barriers: 1 (staging) + 2/chunk = 9 per block (vs 17 in r8); GEMM1'(c+1)
// overlaps GEMM2(c) stragglers because it only reads feat_s.
// LDS 70912 B -> 2 blocks/CU.
__global__ __launch_bounds__(256, 2) void relfeat_mfma_kernel(
    const float* __restrict__ q, const float* __restrict__ k,
    const float* __restrict__ W1, const float* __restrict__ b1,
    const float* __restrict__ W2, const float* __restrict__ b2,
    float* __restrict__ out)
{
    __shared__ __align__(16) short feat_s[NK * FSTRIDE];   // 32768 B
    __shared__ __align__(16) short h_s[64 * HSTRIDE];      // 33792 B
    __shared__ __align__(16) short w2_s[8 * W2S];          //  4224 B

    const int t = threadIdx.x;
    const int wave = t >> 6;
    const int lane15 = t & 15;
    const int quad = (t >> 4) & 3;
    const int b = blockIdx.x >> 8;
    const int i = blockIdx.x & (NQ - 1);

    // ---- features for pair j = t (r5-proven math), swizzled immediate store ----
    {
        const float* kp = k + ((size_t)b * NK + t) * DIN;
        const float k0 = kp[0], k3 = kp[3], k4 = kp[4], k5 = kp[5], k6 = kp[6],
                    k7 = kp[7], k8 = kp[8];
        const float* qp = q + ((size_t)b * NQ + i) * DIN;
        const float q0 = qp[0], q3 = qp[3], q4 = qp[4], q5 = qp[5], q6 = qp[6],
                    q7 = qp[7], q8 = qp[8];

        const float dpx = k3 - q3, dpy = k4 - q4;
        const float dvx = k5 - q5, dvy = k6 - q6;
        const float dist = sqrtf(dpx * dpx + dpy * dpy + 1e-6f);
        const float inv_dist = 1.0f / (dist + 0.1f);
        const float inv_d2 = 1.0f / (dist + 1e-6f);
        const float bear_x = dpx * inv_d2, bear_y = dpy * inv_d2;
        const float ata = bear_x * q7 + bear_y * q8;
        const float aspect = bear_x * k7 + bear_y * k8;
        const float dot_dp_dv = dpx * dvx + dpy * dvy;
        const float speed_sq = dvx * dvx + dvy * dvy;
        const float ttca = tanhf(fmaxf(0.f, -dot_dp_dv / (speed_sq + 1e-6f)));
        const float same_team = (q0 == k0) ? 1.f : 0.f;
        const float q_speed = sqrtf(q5 * q5 + q6 * q6);
        const float k_speed = sqrtf(k5 * k5 + k6 * k6);
        const float delta_speed = k_speed - q_speed;

        float feat[FDIM];
        four4(dist,        feat + 0);
        four4(inv_dist,    feat + 8);
        four4(ata,         feat + 16);
        four4(aspect,      feat + 24);
        four2(dpx,         feat + 32);
        four2(dpy,         feat + 36);
        four2(dvx,         feat + 40);
        four2(dvy,         feat + 44);
        four2(ttca,        feat + 48);
        four2(dist,        feat + 52);
        four2(same_team,   feat + 56);
        four2(delta_speed, feat + 60);

        const int sw = t & 7;  // row-dependent XOR swizzle of 8-short blocks
#pragma unroll
        for (int c8 = 0; c8 < 8; ++c8) {
            uint4 v;
            v.x = pack2(feat[c8 * 8 + 0], feat[c8 * 8 + 1]);
            v.y = pack2(feat[c8 * 8 + 2], feat[c8 * 8 + 3]);
            v.z = pack2(feat[c8 * 8 + 4], feat[c8 * 8 + 5]);
            v.w = pack2(feat[c8 * 8 + 6], feat[c8 * 8 + 7]);
            *(uint4*)&feat_s[t * FSTRIDE + ((c8 ^ sw) * 8)] = v;
        }
    }

    // ---- stage W2^T (o-major, 8 rows, padded stride): w2_s[o][k] = W2[k][o] ----
#pragma unroll
    for (int o = 0; o < NH; ++o) w2_s[o * W2S + t] = f2bf(W2[t * NH + o]);

    // ---- W1 fragments (A operand; one-time, L2-hot) ----
    // w1f[nt][ks]: A[m=lane15][k=quad*8+e] = W1[ks*32+quad*8+e][n0+nt*16+lane15]
    const int n0 = wave * 64;
    bf16x8 w1f[4][2];
#pragma unroll
    for (int nt = 0; nt < 4; ++nt)
#pragma unroll
        for (int ks = 0; ks < 2; ++ks) {
            const float* wp = W1 + (size_t)(ks * 32 + quad * 8) * HIDDEN
                              + (n0 + nt * 16 + lane15);
            bf16x8 v;
#pragma unroll
            for (int e = 0; e < 8; ++e) v[e] = f2bf(wp[(size_t)e * HIDDEN]);
            w1f[nt][ks] = v;
        }
    // bias per (nt, r): hidden = n0 + nt*16 + quad*4 + r
    float4 b1q[4];
#pragma unroll
    for (int nt = 0; nt < 4; ++nt)
        b1q[nt] = *(const float4*)&b1[n0 + nt * 16 + quad * 4];
    const float b2v = (lane15 < NH) ? b2[lane15] : 0.f;

    __syncthreads();  // feat_s + w2_s ready

    // ---- main loop: 4 chunks of 64 pairs ----
    const int swr = lane15 & 7;  // row&7 for feat B-frag reads
#pragma unroll 1
    for (int c = 0; c < 4; ++c) {
        const int p0 = c * 64;

        // GEMM1': acc[nt][mt] -> D[hidden=n0+nt*16+quad*4+r][pair=p0+mt*16+lane15]
        // (reads feat_s only -> overlaps prev chunk's GEMM2 stragglers)
        f32x4 acc[4][4];
#pragma unroll
        for (int nt = 0; nt < 4; ++nt)
#pragma unroll
            for (int mt = 0; mt < 4; ++mt)
                acc[nt][mt] = (f32x4){b1q[nt].x, b1q[nt].y, b1q[nt].z, b1q[nt].w};
#pragma unroll
        for (int ks = 0; ks < 2; ++ks)
#pragma unroll
            for (int mt = 0; mt < 4; ++mt) {
                const int row = p0 + mt * 16 + lane15;
                const bf16x8 fb = *(const bf16x8*)
                    &feat_s[row * FSTRIDE + (((ks * 4 + quad) ^ swr) * 8)];
#pragma unroll
                for (int nt = 0; nt < 4; ++nt)
                    acc[nt][mt] = __builtin_amdgcn_mfma_f32_16x16x32_bf16(
                        w1f[nt][ks], fb, acc[nt][mt], 0, 0, 0);
            }

        __syncthreads();  // h_s(c-1) fully consumed by GEMM2 before overwrite

        // silu -> pack 4 hidden-adjacent bf16 -> one ds_write_b64 per (nt,mt)
#pragma unroll
        for (int nt = 0; nt < 4; ++nt)
#pragma unroll
            for (int mt = 0; mt < 4; ++mt) {
                const int pair = mt * 16 + lane15;
                const int hbase = n0 + nt * 16 + quad * 4;
                float s[4];
#pragma unroll
                for (int r = 0; r < 4; ++r) {
                    const float pv = acc[nt][mt][r];
                    const float e = __builtin_amdgcn_exp2f(pv * -1.44269504f);
                    s[r] = pv * __builtin_amdgcn_rcpf(1.f + e);
                }
                uint2 pk;
                pk.x = pack2(s[0], s[1]);
                pk.y = pack2(s[2], s[3]);
                *(uint2*)&h_s[pair * HSTRIDE + hbase] = pk;
            }
        __syncthreads();  // h_s(c) ready

        // GEMM2: each wave one 16-pair M-tile (all 4 waves busy); K=256
        {
            const int pw = wave * 16;
            f32x4 acc2 = (f32x4){b2v, b2v, b2v, b2v};
#pragma unroll
            for (int ks = 0; ks < 8; ++ks) {
                const bf16x8 ha = *(const bf16x8*)&h_s[(pw + lane15) * HSTRIDE
                                                        + ks * 32 + quad * 8];
                const bf16x8 wb = *(const bf16x8*)&w2_s[(lane15 & 7) * W2S
                                                         + ks * 32 + quad * 8];
                acc2 = __builtin_amdgcn_mfma_f32_16x16x32_bf16(ha, wb, acc2, 0, 0, 0);
            }
            if (lane15 < NH) {
                float* op = out + (((size_t)b * NH + lane15) * NQ + i) * NK
                            + (p0 + pw + quad * 4);
                *(float4*)op = make_float4(acc2[0], acc2[1], acc2[2], acc2[3]);
            }
        }
        // no end barrier: next chunk's GEMM1' touches only feat_s; the
        // pre-silu barrier (next iter) protects h_s reuse.
    }
}

extern "C" void kernel_launch(void* const* d_in, const int* in_sizes, int n_in,
                              void* d_out, int out_size, void* d_ws, size_t ws_size,
                              hipStream_t stream) {
    const float* q  = (const float*)d_in[0];
    const float* k  = (const float*)d_in[1];
    const float* W1 = (const float*)d_in[2];
    const float* b1 = (const float*)d_in[3];
    const float* W2 = (const float*)d_in[4];
    const float* b2 = (const float*)d_in[5];
    float* out = (float*)d_out;

    dim3 grid(NB * NQ);   // 2048 blocks: one per (b, i)
    dim3 block(NK);       // 256 threads = 4 waves
    relfeat_mfma_kernel<<<grid, block, 0, stream>>>(q, k, W1, b1, W2, b2, out);
}

// Round 10
// 113.258 us; speedup vs baseline: 1.0486x; 1.0265x over previous
//
#include <hip/hip_runtime.h>
#include <math.h>

#define NB 8
#define NQ 256
#define NK 256
#define DIN 10
#define FDIM 64
#define HIDDEN 256
#define NH 8
#define ROWS_PER_BLK 4

#define FSTRIDE 64    // shorts per feat row; XOR-swizzled 8-short col-blocks, no pad
#define HSTRIDE 264   // shorts per h row (256 + 8 pad) -> 528 B
#define W2S 264       // shorts per w2 row (8 rows, padded -> 528 B)

typedef float f32x4 __attribute__((ext_vector_type(4)));
typedef short bf16x8 __attribute__((ext_vector_type(8)));

// fast float->bf16: round-to-nearest, ties away (2 instrs)
__device__ __forceinline__ short f2bf(float f) {
    return (short)((__float_as_uint(f) + 0x8000u) >> 16);
}
// pack two floats -> two bf16 in one dword (2 adds + 1 perm)
__device__ __forceinline__ unsigned pack2(float a, float b) {
    unsigned ua = __float_as_uint(a) + 0x8000u;   // -> low half
    unsigned ub = __float_as_uint(b) + 0x8000u;   // -> high half
    return __builtin_amdgcn_perm(ub, ua, 0x07060302);
}

__device__ __forceinline__ void four4(float x, float* dst) {
    float s1 = __sinf(x), c1 = __cosf(x);
    float s2 = 2.f * s1 * c1, c2 = 1.f - 2.f * s1 * s1;
    float s4 = 2.f * s2 * c2, c4 = 1.f - 2.f * s2 * s2;
    float s8 = 2.f * s4 * c4, c8 = 1.f - 2.f * s4 * s4;
    dst[0] = s1; dst[1] = s2; dst[2] = s4; dst[3] = s8;
    dst[4] = c1; dst[5] = c2; dst[6] = c4; dst[7] = c8;
}
__device__ __forceinline__ void four2(float x, float* dst) {
    float s1 = __sinf(x), c1 = __cosf(x);
    dst[0] = s1; dst[1] = 2.f * s1 * c1;
    dst[2] = c1; dst[3] = 1.f - 2.f * s1 * s1;
}

// Block = one (b, i0..i0+3): FOUR query rows, 256 pairs each; 4 waves.
// Grid = 512 = exactly 2 blocks/CU resident in ONE dispatch round.
// Per row: r9's proven pipeline (transposed GEMM1, 4 chunks of 64 pairs,
// all-wave GEMM2). W1 frags / w2_s / k-rows loaded ONCE per block.
// Scale folds: W1,b1 pre-scaled by -log2(e) so GEMM1 acc is the exp2 arg;
// W2 pre-scaled by -ln(2) to compensate: (-1.4427*silu)·(-0.6931*W2)=silu·W2.
// silu = exp2, add, rcp, mul (4 instrs).
// LDS 70912 B -> 2 blocks/CU.
__global__ __launch_bounds__(256, 2) void relfeat_mfma_kernel(
    const float* __restrict__ q, const float* __restrict__ k,
    const float* __restrict__ W1, const float* __restrict__ b1,
    const float* __restrict__ W2, const float* __restrict__ b2,
    float* __restrict__ out)
{
    __shared__ __align__(16) short feat_s[NK * FSTRIDE];   // 32768 B
    __shared__ __align__(16) short h_s[64 * HSTRIDE];      // 33792 B
    __shared__ __align__(16) short w2_s[8 * W2S];          //  4224 B

    const int t = threadIdx.x;
    const int wave = t >> 6;
    const int lane15 = t & 15;
    const int quad = (t >> 4) & 3;
    const int b = blockIdx.x >> 6;
    const int i0 = (blockIdx.x & 63) * ROWS_PER_BLK;

    // ---- k-row for pair j = t: block-invariant, cache in regs ----
    const float* kp = k + ((size_t)b * NK + t) * DIN;
    const float k0 = kp[0], k3 = kp[3], k4 = kp[4], k5 = kp[5], k6 = kp[6],
                k7 = kp[7], k8 = kp[8];

    // ---- stage W2^T scaled by -ln2 (o-major, padded stride) ----
#pragma unroll
    for (int o = 0; o < NH; ++o)
        w2_s[o * W2S + t] = f2bf(-0.69314718f * W2[t * NH + o]);

    // ---- W1 fragments (A operand), scaled by -log2e; one-time, L2-hot ----
    const int n0 = wave * 64;
    bf16x8 w1f[4][2];
#pragma unroll
    for (int nt = 0; nt < 4; ++nt)
#pragma unroll
        for (int ks = 0; ks < 2; ++ks) {
            const float* wp = W1 + (size_t)(ks * 32 + quad * 8) * HIDDEN
                              + (n0 + nt * 16 + lane15);
            bf16x8 v;
#pragma unroll
            for (int e = 0; e < 8; ++e)
                v[e] = f2bf(-1.44269504f * wp[(size_t)e * HIDDEN]);
            w1f[nt][ks] = v;
        }
    // bias per (nt, r), scaled by -log2e
    float4 b1q[4];
#pragma unroll
    for (int nt = 0; nt < 4; ++nt) {
        float4 bb = *(const float4*)&b1[n0 + nt * 16 + quad * 4];
        b1q[nt] = make_float4(-1.44269504f * bb.x, -1.44269504f * bb.y,
                              -1.44269504f * bb.z, -1.44269504f * bb.w);
    }
    const float b2v = (lane15 < NH) ? b2[lane15] : 0.f;

    const int sw = t & 7;        // feature-store swizzle
    const int swr = lane15 & 7;  // feat B-frag read swizzle

    // ================= row loop: 4 query rows =================
#pragma unroll 1
    for (int row = 0; row < ROWS_PER_BLK; ++row) {
        const int i = i0 + row;

        // ---- features for pair (i, j=t): r5-proven math, swizzled store ----
        {
            const float* qp = q + ((size_t)b * NQ + i) * DIN;
            const float q0 = qp[0], q3 = qp[3], q4 = qp[4], q5 = qp[5],
                        q6 = qp[6], q7 = qp[7], q8 = qp[8];

            const float dpx = k3 - q3, dpy = k4 - q4;
            const float dvx = k5 - q5, dvy = k6 - q6;
            const float dist = sqrtf(dpx * dpx + dpy * dpy + 1e-6f);
            const float inv_dist = 1.0f / (dist + 0.1f);
            const float inv_d2 = 1.0f / (dist + 1e-6f);
            const float bear_x = dpx * inv_d2, bear_y = dpy * inv_d2;
            const float ata = bear_x * q7 + bear_y * q8;
            const float aspect = bear_x * k7 + bear_y * k8;
            const float dot_dp_dv = dpx * dvx + dpy * dvy;
            const float speed_sq = dvx * dvx + dvy * dvy;
            const float ttca = tanhf(fmaxf(0.f, -dot_dp_dv / (speed_sq + 1e-6f)));
            const float same_team = (q0 == k0) ? 1.f : 0.f;
            const float q_speed = sqrtf(q5 * q5 + q6 * q6);
            const float k_speed = sqrtf(k5 * k5 + k6 * k6);
            const float delta_speed = k_speed - q_speed;

            float feat[FDIM];
            four4(dist,        feat + 0);
            four4(inv_dist,    feat + 8);
            four4(ata,         feat + 16);
            four4(aspect,      feat + 24);
            four2(dpx,         feat + 32);
            four2(dpy,         feat + 36);
            four2(dvx,         feat + 40);
            four2(dvy,         feat + 44);
            four2(ttca,        feat + 48);
            four2(dist,        feat + 52);
            four2(same_team,   feat + 56);
            four2(delta_speed, feat + 60);

#pragma unroll
            for (int c8 = 0; c8 < 8; ++c8) {
                uint4 v;
                v.x = pack2(feat[c8 * 8 + 0], feat[c8 * 8 + 1]);
                v.y = pack2(feat[c8 * 8 + 2], feat[c8 * 8 + 3]);
                v.z = pack2(feat[c8 * 8 + 4], feat[c8 * 8 + 5]);
                v.w = pack2(feat[c8 * 8 + 6], feat[c8 * 8 + 7]);
                *(uint4*)&feat_s[t * FSTRIDE + ((c8 ^ sw) * 8)] = v;
            }
        }
        // Safe: all feat_s readers of row-1 finished before row-1's last
        // pre-silu barrier; all h_s readers finished before this barrier.
        __syncthreads();  // feat_s(row) + (row 0: w2_s) ready

        // ---- 4 chunks of 64 pairs ----
#pragma unroll 1
        for (int c = 0; c < 4; ++c) {
            const int p0 = c * 64;

            // GEMM1': acc[nt][mt] -> D[hidden=n0+nt*16+quad*4+r][pair=p0+mt*16+lane15]
            f32x4 acc[4][4];
#pragma unroll
            for (int nt = 0; nt < 4; ++nt)
#pragma unroll
                for (int mt = 0; mt < 4; ++mt)
                    acc[nt][mt] = (f32x4){b1q[nt].x, b1q[nt].y, b1q[nt].z, b1q[nt].w};
#pragma unroll
            for (int ks = 0; ks < 2; ++ks)
#pragma unroll
                for (int mt = 0; mt < 4; ++mt) {
                    const int r2 = p0 + mt * 16 + lane15;
                    const bf16x8 fb = *(const bf16x8*)
                        &feat_s[r2 * FSTRIDE + (((ks * 4 + quad) ^ swr) * 8)];
#pragma unroll
                    for (int nt = 0; nt < 4; ++nt)
                        acc[nt][mt] = __builtin_amdgcn_mfma_f32_16x16x32_bf16(
                            w1f[nt][ks], fb, acc[nt][mt], 0, 0, 0);
                }

            __syncthreads();  // h_s(prev) fully consumed before overwrite

            // silu (scale-folded, 4 instrs) -> pack -> one ds_write_b64
#pragma unroll
            for (int nt = 0; nt < 4; ++nt)
#pragma unroll
                for (int mt = 0; mt < 4; ++mt) {
                    const int pair = mt * 16 + lane15;
                    const int hbase = n0 + nt * 16 + quad * 4;
                    float s[4];
#pragma unroll
                    for (int r = 0; r < 4; ++r) {
                        const float a = acc[nt][mt][r];     // = -log2e * preact
                        const float e = __builtin_amdgcn_exp2f(a);
                        s[r] = a * __builtin_amdgcn_rcpf(1.f + e);  // -1.4427*silu
                    }
                    uint2 pk;
                    pk.x = pack2(s[0], s[1]);
                    pk.y = pack2(s[2], s[3]);
                    *(uint2*)&h_s[pair * HSTRIDE + hbase] = pk;
                }
            __syncthreads();  // h_s(c) ready

            // GEMM2: each wave one 16-pair M-tile; K=256; W2 carries -ln2
            {
                const int pw = wave * 16;
                f32x4 acc2 = (f32x4){b2v, b2v, b2v, b2v};
#pragma unroll
                for (int ks = 0; ks < 8; ++ks) {
                    const bf16x8 ha = *(const bf16x8*)&h_s[(pw + lane15) * HSTRIDE
                                                            + ks * 32 + quad * 8];
                    const bf16x8 wb = *(const bf16x8*)&w2_s[(lane15 & 7) * W2S
                                                             + ks * 32 + quad * 8];
                    acc2 = __builtin_amdgcn_mfma_f32_16x16x32_bf16(ha, wb, acc2, 0, 0, 0);
                }
                if (lane15 < NH) {
                    float* op = out + (((size_t)b * NH + lane15) * NQ + i) * NK
                                + (p0 + pw + quad * 4);
                    *(float4*)op = make_float4(acc2[0], acc2[1], acc2[2], acc2[3]);
                }
            }
            // no end barrier: next chunk's GEMM1' touches only feat_s
        }
    }
}

extern "C" void kernel_launch(void* const* d_in, const int* in_sizes, int n_in,
                              void* d_out, int out_size, void* d_ws, size_t ws_size,
                              hipStream_t stream) {
    const float* q  = (const float*)d_in[0];
    const float* k  = (const float*)d_in[1];
    const float* W1 = (const float*)d_in[2];
    const float* b1 = (const float*)d_in[3];
    const float* W2 = (const float*)d_in[4];
    const float* b2 = (const float*)d_in[5];
    float* out = (float*)d_out;

    dim3 grid(NB * NQ / ROWS_PER_BLK);  // 512 blocks = 2/CU, one dispatch round
    dim3 block(NK);                     // 256 threads = 4 waves
    relfeat_mfma_kernel<<<grid, block, 0, stream>>>(q, k, W1, b1, W2, b2, out);
}